// Round 9
// baseline (626.128 us; speedup 1.0000x reference)
//
#include <hip/hip_runtime.h>

#define HH 384
#define WW 384
#define HWSZ (HH * WW)
#define NIMG 24

typedef float v2f __attribute__((ext_vector_type(2)));

__device__ __forceinline__ int refl(int i, int n) {
    if (i < 0) i = -i;
    if (i >= n) i = 2 * n - 2 - i;
    return i;
}

// 5-tap Gaussian (sigma=1, normalized) as constexpr -> inline literals
constexpr float LPW[5] = {
    0.054488684549642945f, 0.24420134200323332f, 0.40261994689424746f,
    0.24420134200323332f, 0.054488684549642945f
};

// ===================== compile-time filter generation =======================
// constexpr fp64 math (range-reduced Taylor / Newton); error ~1e-16 rel.
// Numerically validated rounds 5-8 (absmax identical to runtime fp64 gen).
constexpr double CPI = 3.141592653589793;  // == numpy.pi as double

constexpr double cexp(double x) {
    int k = 0; double t = x;
    while (t > 0.25 || t < -0.25) { t *= 0.5; ++k; }
    double sum = 1.0, term = 1.0;
    for (int n = 1; n <= 14; ++n) { term *= t / n; sum += term; }
    for (int i = 0; i < k; ++i) sum *= sum;
    return sum;
}
constexpr double ccos(double x) {   // x in [0, pi)
    double sgn = 1.0;
    if (x > CPI * 0.5) { x = CPI - x; sgn = -1.0; }
    double x2 = x * x, sum = 1.0, term = 1.0;
    for (int n = 1; n <= 12; ++n) { term *= -x2 / ((2.0 * n - 1) * (2.0 * n)); sum += term; }
    return sgn * sum;
}
constexpr double csin(double x) {   // x in [0, pi)
    if (x > CPI * 0.5) x = CPI - x;
    double x2 = x * x, sum = x, term = x;
    for (int n = 1; n <= 12; ++n) { term *= -x2 / ((2.0 * n) * (2.0 * n + 1)); sum += term; }
    return sum;
}
constexpr double csqrt(double x) {
    if (x <= 0.0) return 0.0;
    double y = x > 1.0 ? x : 1.0;
    for (int i = 0; i < 80; ++i) y = 0.5 * (y + x / y);
    return y;
}

struct F225 { double v[225]; };

constexpr F225 make_filter(int s, int d, int nd) {
    double angle = CPI * (double)d / (double)nd;
    double scale = (double)(s + 1);
    double sx = 2.0 * scale, sy = 0.5 * scale;
    double ca = ccos(angle), sa = csin(angle);
    F225 f{};
    double sum = 0.0;
    for (int r = 0; r < 15; ++r)
        for (int c = 0; c < 15; ++c) {
            double X = (double)(c - 7), Y = (double)(r - 7);
            double Xr = X * ca - Y * sa;
            double Yr = X * sa + Y * ca;
            double k = cexp(-0.5 * (Xr * Xr / (sx * sx) + Yr * Yr / (sy * sy))) * Xr / (sx * sx);
            f.v[r * 15 + c] = k; sum += k;
        }
    double mean = sum / 225.0;
    double ss = 0.0;
    for (int i = 0; i < 225; ++i) { f.v[i] -= mean; ss += f.v[i] * f.v[i]; }
    double n = csqrt(ss);
    if (n > 1e-6) for (int i = 0; i < 225; ++i) f.v[i] /= n;
    return f;
}

template <int S, int D>
struct Filt { static constexpr F225 v = make_filter(S, D, S == 0 ? 4 : (S == 1 ? 8 : 16)); };

constexpr const F225& getF(int s, int d) {
    if (s == 0) {
        if (d == 0) return Filt<0, 0>::v;
        if (d == 1) return Filt<0, 1>::v;
        return Filt<0, 2>::v;
    } else if (s == 1) {
        if (d == 0) return Filt<1, 0>::v;
        if (d == 1) return Filt<1, 1>::v;
        if (d == 2) return Filt<1, 2>::v;
        if (d == 3) return Filt<1, 3>::v;
        return Filt<1, 4>::v;
    } else {
        if (d == 0) return Filt<2, 0>::v;
        if (d == 1) return Filt<2, 1>::v;
        if (d == 2) return Filt<2, 2>::v;
        if (d == 3) return Filt<2, 3>::v;
        if (d == 4) return Filt<2, 4>::v;
        if (d == 5) return Filt<2, 5>::v;
        if (d == 6) return Filt<2, 6>::v;
        if (d == 7) return Filt<2, 7>::v;
        return Filt<2, 8>::v;
    }
}

// Packed mirror-pair tables (algebra verified rounds 3-8):
// point-antisymmetry G(-u,-v) = -G(u,v); x-mirror G_{nd-d}(u,v) = G_d(u,-v).
// out_d = P + Q, out_{nd-d} = P - Q;
//   A(j,k) = (G_dP(u,v)+G_dP(u,-v))/2, dP = (k==0 ? NH : k)
//   B(j,k) = (G_dQ(u,v)-G_dQ(u,-v))/2, dQ = (k==0 ? 0  : k)
// positions j: 0..6 (0,v) [A==0], 7..13 (u,0) [B==0], 14..62 (u,v) u,v>=1.
template <int NH> struct PTab { float a[63 * NH]; float b[63 * NH]; };

template <int NH>
constexpr PTab<NH> make_ptab(int s) {
    PTab<NH> t{};
    for (int j = 0; j < 63; ++j) {
        int u, v;
        if (j < 7)       { u = 0;     v = j + 1; }
        else if (j < 14) { u = j - 6; v = 0;     }
        else { int p = j - 14; u = p / 7 + 1; v = p % 7 + 1; }
        for (int k = 0; k < NH; ++k) {
            int dP = (k == 0) ? NH : k;
            int dQ = (k == 0) ? 0 : k;
            const F225& FP = getF(s, dP);
            const F225& FQ = getF(s, dQ);
            double A = 0.5 * (FP.v[(7 + u) * 15 + (7 + v)] + FP.v[(7 + u) * 15 + (7 - v)]);
            double B = 0.5 * (FQ.v[(7 + u) * 15 + (7 + v)] - FQ.v[(7 + u) * 15 + (7 - v)]);
            t.a[j * NH + k] = (float)A;
            t.b[j * NH + k] = (float)B;
        }
    }
    return t;
}
template <int S, int NH>
struct PTbl { static constexpr PTab<NH> t = make_ptab<NH>(S); };

// ===================== packed-FMA building blocks ===========================
constexpr unsigned fb(float f) { return __builtin_bit_cast(unsigned, f); }
constexpr unsigned long long fb2(float lo, float hi) {
    return ((unsigned long long)fb(hi) << 32) | (unsigned long long)fb(lo);
}

// acc.{lo,hi} += sd.lo * {Clo,Chi} : one VOP3P inst = 2 FMAs; coef pair lives
// in an SGPR pair (2 s_mov on the scalar pipe, off the VALU critical path).
template <unsigned long long C>
__device__ __forceinline__ void pkfma_lo(v2f& acc, v2f sd) {
    asm("v_pk_fma_f32 %0, %1, %2, %0 op_sel:[0,0,0] op_sel_hi:[0,1,1]"
        : "+v"(acc) : "v"(sd), "s"(C));
}
// acc.{lo,hi} += sd.hi * {Clo,Chi}
template <unsigned long long C>
__device__ __forceinline__ void pkfma_hi(v2f& acc, v2f sd) {
    asm("v_pk_fma_f32 %0, %1, %2, %0 op_sel:[1,0,0] op_sel_hi:[1,1,1]"
        : "+v"(acc) : "v"(sd), "s"(C));
}

// Both streams at position J: sd.x = S -> P (A coefs), sd.y = D -> Q (B coefs).
template <int SIDX, int NH, int J, int PX, int K2 = 0>
struct AccSD {
    static __device__ __forceinline__ void run(v2f (&P)[PX][NH / 2], v2f (&Q)[PX][NH / 2],
                                               const v2f (&sd)[PX]) {
        constexpr unsigned long long CA = fb2(PTbl<SIDX, NH>::t.a[J * NH + 2 * K2],
                                              PTbl<SIDX, NH>::t.a[J * NH + 2 * K2 + 1]);
        constexpr unsigned long long CB = fb2(PTbl<SIDX, NH>::t.b[J * NH + 2 * K2],
                                              PTbl<SIDX, NH>::t.b[J * NH + 2 * K2 + 1]);
#pragma unroll
        for (int j = 0; j < PX; ++j) pkfma_lo<CA>(P[j][K2], sd[j]);
#pragma unroll
        for (int j = 0; j < PX; ++j) pkfma_hi<CB>(Q[j][K2], sd[j]);
        if constexpr (K2 + 1 < NH / 2) AccSD<SIDX, NH, J, PX, K2 + 1>::run(P, Q, sd);
    }
};
// Single stream at position J (value in sd.x): USEA -> A table, else B table.
template <int SIDX, int NH, int J, int PX, bool USEA, int K2 = 0>
struct AccOne {
    static __device__ __forceinline__ void run(v2f (&T)[PX][NH / 2], const v2f (&sd)[PX]) {
        constexpr unsigned long long C = USEA
            ? fb2(PTbl<SIDX, NH>::t.a[J * NH + 2 * K2], PTbl<SIDX, NH>::t.a[J * NH + 2 * K2 + 1])
            : fb2(PTbl<SIDX, NH>::t.b[J * NH + 2 * K2], PTbl<SIDX, NH>::t.b[J * NH + 2 * K2 + 1]);
#pragma unroll
        for (int j = 0; j < PX; ++j) pkfma_lo<C>(T[j][K2], sd[j]);
        if constexpr (K2 + 1 < NH / 2) AccOne<SIDX, NH, J, PX, USEA, K2 + 1>::run(T, sd);
    }
};

// H0: u=0, v=1..7 (j=v-1): A==0, Q only.
template <int SIDX, int NH, int PX, int W, int V = 1>
struct H0Step {
    static __device__ __forceinline__ void run(const float (&w0)[W], v2f (&Q)[PX][NH / 2]) {
        v2f sd[PX];
#pragma unroll
        for (int j = 0; j < PX; ++j) sd[j].x = w0[7 + V + j] - w0[7 - V + j];
        AccOne<SIDX, NH, V - 1, PX, false>::run(Q, sd);
        if constexpr (V < 7) H0Step<SIDX, NH, PX, W, V + 1>::run(w0, Q);
    }
};

// Hp: v=1..7 for one u: S->P, D->Q.
template <int SIDX, int NH, int PX, int W, int U, int V = 1>
struct VStep {
    static __device__ __forceinline__ void run(const float (&wp)[W], const float (&wm)[W],
                                               v2f (&P)[PX][NH / 2], v2f (&Q)[PX][NH / 2]) {
        v2f sd[PX];
#pragma unroll
        for (int j = 0; j < PX; ++j) {
            float t1 = wp[7 + V + j] - wm[7 - V + j];
            float t2 = wp[7 - V + j] - wm[7 + V + j];
            sd[j].x = t1 + t2;
            sd[j].y = t1 - t2;
        }
        AccSD<SIDX, NH, 14 + (U - 1) * 7 + (V - 1), PX>::run(P, Q, sd);
        if constexpr (V < 7) VStep<SIDX, NH, PX, W, U, V + 1>::run(wp, wm, P, Q);
    }
};

// u = 1..7. Per u-step: load the two 16/18-float row windows ONCE (compiler
// merges consecutive scalar LDS reads into ds_read2_b32 — halves LDS insts
// vs per-position loads). Memory-clobber fence per u-step bounds the
// scheduling window (round-5 lesson: unfenced body spills to scratch).
template <int SIDX, int NH, int PX, int W, int U = 1>
struct UStep {
    static __device__ __forceinline__ void run(const float* sm, int yb, int xg,
                                               v2f (&P)[PX][NH / 2], v2f (&Q)[PX][NH / 2]) {
        float wp[W], wm[W];
#pragma unroll
        for (int i = 0; i < W; ++i) wp[i] = sm[(yb + U) * 49 + xg + i];
#pragma unroll
        for (int i = 0; i < W; ++i) wm[i] = sm[(yb - U) * 49 + xg + i];
        {   // Hc: v=0 (j=6+U): B==0, P only
            v2f sd[PX];
#pragma unroll
            for (int j = 0; j < PX; ++j) sd[j].x = wp[7 + j] - wm[7 + j];
            AccOne<SIDX, NH, 6 + U, PX, true>::run(P, sd);
        }
        VStep<SIDX, NH, PX, W, U>::run(wp, wm, P, Q);
        asm volatile("" ::: "memory");
        if constexpr (U < 7) UStep<SIDX, NH, PX, W, U + 1>::run(sm, yb, xg, P, Q);
    }
};

// One band over a 32x32 tile. PX adjacent x-pixels per thread; 4/PX row-iters.
// PX=4 for NH=2,4 (fewer LDS reads); PX=2 for NH=8 (VGPR control).
// sm: flat LDS band tile, stride 49 (odd keeps row aliasing <=2-way), halo 7.
template <int SIDX, int NH, int PX>
__device__ __forceinline__ void dir_band(
    const float* sm, float* __restrict__ out, long nbase,
    int by, int bx, int lane, int c0) {
    constexpr int W = 14 + PX;
    constexpr int LPR = 32 / PX;   // threads per tile row
    int xg = (lane % LPR) * PX;
    int yr = lane / LPR;
#pragma unroll 1
    for (int rr = 0; rr < 4 / PX; ++rr) {
        int y = yr + 8 * PX * rr;
        int yb = y + 7;
        v2f P[PX][NH / 2], Q[PX][NH / 2];
#pragma unroll
        for (int j = 0; j < PX; ++j)
#pragma unroll
            for (int k = 0; k < NH / 2; ++k) {
                P[j][k] = (v2f){0.f, 0.f};
                Q[j][k] = (v2f){0.f, 0.f};
            }
        {
            float w0[W];
#pragma unroll
            for (int i = 0; i < W; ++i) w0[i] = sm[yb * 49 + xg + i];
            H0Step<SIDX, NH, PX, W>::run(w0, Q);
        }
        asm volatile("" ::: "memory");
        UStep<SIDX, NH, PX, W>::run(sm, yb, xg, P, Q);

        // d=0 -> Q[0].x; d=NH -> P[0].x; pair k: d=k -> P+Q, d=2NH-k -> P-Q
        long idx0 = nbase + (long)c0 * HWSZ + (long)(by + y) * WW + bx + xg;
#pragma unroll
        for (int j = 0; j < PX; ++j) out[idx0 + j] = Q[j][0].x;
#pragma unroll
        for (int j = 0; j < PX; ++j) out[idx0 + (long)NH * HWSZ + j] = P[j][0].x;
#pragma unroll
        for (int k = 1; k < NH; ++k) {
#pragma unroll
            for (int j = 0; j < PX; ++j) {
                float p = (k & 1) ? P[j][k >> 1].y : P[j][k >> 1].x;
                float q = (k & 1) ? Q[j][k >> 1].y : Q[j][k >> 1].x;
                out[idx0 + (long)k * HWSZ + j] = p + q;
                out[idx0 + (long)(2 * NH - k) * HWSZ + j] = p - q;
            }
        }
    }
}

// ===================== fully-fused NSST kernel ==============================
// Per 32x32 tile: stage x with halo 13 (reflect) -> lp chain in LDS ->
// band0/1/2 materialized in LDS (stride 49) -> three dir banks. Zero
// intermediate HBM traffic. Buffer recycling:
//   Xb: x[58][60]            -> lp1[50][52]
//   Tb: h0[58][56] -> band0[46][49] -> h1[54][52] -> band1 -> h2[50][48] -> band2
//   Pb: lp0[54][56]          -> lp2[46][48]
__global__ __launch_bounds__(256, 4) void nsst_fused(
    const float* __restrict__ x, float* __restrict__ out) {
    __shared__ float Xb[58 * 60];
    __shared__ float Tb[58 * 56];
    __shared__ float Pb[54 * 56];

    int n = blockIdx.z;
    int bx = blockIdx.x * 32, by = blockIdx.y * 32;
    int tx = threadIdx.x, ty = threadIdx.y;
    int lane = ty * 32 + tx;
    const float* ip = x + (long)n * HWSZ;
    long nbase = (long)n * 29 * HWSZ;

    // stage x[-13..44]^2 (58x58), reflect at input indexing (2D strides: no div)
    for (int r = ty; r < 58; r += 8) {
        int gy = refl(by + r - 13, HH);
        for (int c = tx; c < 58; c += 32)
            Xb[r * 60 + c] = ip[(long)gy * WW + refl(bx + c - 13, WW)];
    }
    __syncthreads();
    // h0 = H(x): 58 rows x 54 cols, Tb stride 56
    for (int r = ty; r < 58; r += 8)
        for (int c = tx; c < 54; c += 32) {
            float s = 0.f;
#pragma unroll
            for (int i = 0; i < 5; ++i) s = fmaf(LPW[i], Xb[r * 60 + c + i], s);
            Tb[r * 56 + c] = s;
        }
    __syncthreads();
    // lp0 = V(h0): 54x54, Pb stride 56
    for (int r = ty; r < 54; r += 8)
        for (int c = tx; c < 54; c += 32) {
            float s = 0.f;
#pragma unroll
            for (int i = 0; i < 5; ++i) s = fmaf(LPW[i], Tb[(r + i) * 56 + c], s);
            Pb[r * 56 + c] = s;
        }
    __syncthreads();
    // band0 = x - lp0 on 46x46, Tb stride 49
    for (int r = ty; r < 46; r += 8)
        for (int c = tx; c < 46; c += 32)
            Tb[r * 49 + c] = Xb[(r + 6) * 60 + c + 6] - Pb[(r + 4) * 56 + c + 4];
    __syncthreads();
    dir_band<0, 2, 4>(Tb, out, nbase, by, bx, lane, 0);   // channels 0..3
    __syncthreads();
    // h1 = H(lp0): 54 rows x 50 cols, Tb stride 52
    for (int r = ty; r < 54; r += 8)
        for (int c = tx; c < 50; c += 32) {
            float s = 0.f;
#pragma unroll
            for (int i = 0; i < 5; ++i) s = fmaf(LPW[i], Pb[r * 56 + c + i], s);
            Tb[r * 52 + c] = s;
        }
    __syncthreads();
    // lp1 = V(h1): 50x50, Xb stride 52 (x is dead)
    for (int r = ty; r < 50; r += 8)
        for (int c = tx; c < 50; c += 32) {
            float s = 0.f;
#pragma unroll
            for (int i = 0; i < 5; ++i) s = fmaf(LPW[i], Tb[(r + i) * 52 + c], s);
            Xb[r * 52 + c] = s;
        }
    __syncthreads();
    // band1 = lp0 - lp1 on 46x46, Tb stride 49
    for (int r = ty; r < 46; r += 8)
        for (int c = tx; c < 46; c += 32)
            Tb[r * 49 + c] = Pb[(r + 4) * 56 + c + 4] - Xb[(r + 2) * 52 + c + 2];
    __syncthreads();
    dir_band<1, 4, 4>(Tb, out, nbase, by, bx, lane, 4);   // channels 4..11
    __syncthreads();
    // h2 = H(lp1): 50 rows x 46 cols, Tb stride 48
    for (int r = ty; r < 50; r += 8)
        for (int c = tx; c < 46; c += 32) {
            float s = 0.f;
#pragma unroll
            for (int i = 0; i < 5; ++i) s = fmaf(LPW[i], Xb[r * 52 + c + i], s);
            Tb[r * 48 + c] = s;
        }
    __syncthreads();
    // lp2 = V(h2): 46x46, Pb stride 48 (lp0 dead)
    for (int r = ty; r < 46; r += 8)
        for (int c = tx; c < 46; c += 32) {
            float s = 0.f;
#pragma unroll
            for (int i = 0; i < 5; ++i) s = fmaf(LPW[i], Tb[(r + i) * 48 + c], s);
            Pb[r * 48 + c] = s;
        }
    __syncthreads();
    // channel 28 = lp2 center
#pragma unroll
    for (int rr = 0; rr < 4; ++rr)
        out[nbase + 28l * HWSZ + (long)(by + ty + 8 * rr) * WW + bx + tx] =
            Pb[(ty + 8 * rr + 7) * 48 + tx + 7];
    // band2 = lp1 - lp2 on 46x46, Tb stride 49 (h2 dead)
    for (int r = ty; r < 46; r += 8)
        for (int c = tx; c < 46; c += 32)
            Tb[r * 49 + c] = Xb[(r + 2) * 52 + c + 2] - Pb[r * 48 + c];
    __syncthreads();
    dir_band<2, 8, 2>(Tb, out, nbase, by, bx, lane, 12);  // channels 12..27
}

extern "C" void kernel_launch(void* const* d_in, const int* in_sizes, int n_in,
                              void* d_out, int out_size, void* d_ws, size_t ws_size,
                              hipStream_t stream) {
    const float* x = (const float*)d_in[0];
    float* out = (float*)d_out;
    (void)d_ws; (void)ws_size;

    nsst_fused<<<dim3(12, 12, NIMG), dim3(32, 8), 0, stream>>>(x, out);
}

// Round 10
// 545.662 us; speedup vs baseline: 1.1475x; 1.1475x over previous
//
#include <hip/hip_runtime.h>

#define HH 384
#define WW 384
#define HWSZ (HH * WW)
#define NIMG 24

typedef float v2f __attribute__((ext_vector_type(2)));
typedef float v4f __attribute__((ext_vector_type(4)));

__device__ __forceinline__ int refl(int i, int n) {
    if (i < 0) i = -i;
    if (i >= n) i = 2 * n - 2 - i;
    return i;
}

// 5-tap Gaussian (sigma=1, normalized) as constexpr -> inline literals
constexpr float LPW[5] = {
    0.054488684549642945f, 0.24420134200323332f, 0.40261994689424746f,
    0.24420134200323332f, 0.054488684549642945f
};

// ===================== compile-time filter generation =======================
// constexpr fp64 math (range-reduced Taylor / Newton); error ~1e-16 rel.
// Numerically validated rounds 5-9 (absmax identical to runtime fp64 gen).
constexpr double CPI = 3.141592653589793;  // == numpy.pi as double

constexpr double cexp(double x) {
    int k = 0; double t = x;
    while (t > 0.25 || t < -0.25) { t *= 0.5; ++k; }
    double sum = 1.0, term = 1.0;
    for (int n = 1; n <= 14; ++n) { term *= t / n; sum += term; }
    for (int i = 0; i < k; ++i) sum *= sum;
    return sum;
}
constexpr double ccos(double x) {   // x in [0, pi)
    double sgn = 1.0;
    if (x > CPI * 0.5) { x = CPI - x; sgn = -1.0; }
    double x2 = x * x, sum = 1.0, term = 1.0;
    for (int n = 1; n <= 12; ++n) { term *= -x2 / ((2.0 * n - 1) * (2.0 * n)); sum += term; }
    return sgn * sum;
}
constexpr double csin(double x) {   // x in [0, pi)
    if (x > CPI * 0.5) x = CPI - x;
    double x2 = x * x, sum = x, term = x;
    for (int n = 1; n <= 12; ++n) { term *= -x2 / ((2.0 * n) * (2.0 * n + 1)); sum += term; }
    return sum;
}
constexpr double csqrt(double x) {
    if (x <= 0.0) return 0.0;
    double y = x > 1.0 ? x : 1.0;
    for (int i = 0; i < 80; ++i) y = 0.5 * (y + x / y);
    return y;
}

struct F225 { double v[225]; };

constexpr F225 make_filter(int s, int d, int nd) {
    double angle = CPI * (double)d / (double)nd;
    double scale = (double)(s + 1);
    double sx = 2.0 * scale, sy = 0.5 * scale;
    double ca = ccos(angle), sa = csin(angle);
    F225 f{};
    double sum = 0.0;
    for (int r = 0; r < 15; ++r)
        for (int c = 0; c < 15; ++c) {
            double X = (double)(c - 7), Y = (double)(r - 7);
            double Xr = X * ca - Y * sa;
            double Yr = X * sa + Y * ca;
            double k = cexp(-0.5 * (Xr * Xr / (sx * sx) + Yr * Yr / (sy * sy))) * Xr / (sx * sx);
            f.v[r * 15 + c] = k; sum += k;
        }
    double mean = sum / 225.0;
    double ss = 0.0;
    for (int i = 0; i < 225; ++i) { f.v[i] -= mean; ss += f.v[i] * f.v[i]; }
    double n = csqrt(ss);
    if (n > 1e-6) for (int i = 0; i < 225; ++i) f.v[i] /= n;
    return f;
}

template <int S, int D>
struct Filt { static constexpr F225 v = make_filter(S, D, S == 0 ? 4 : (S == 1 ? 8 : 16)); };

constexpr const F225& getF(int s, int d) {
    if (s == 0) {
        if (d == 0) return Filt<0, 0>::v;
        if (d == 1) return Filt<0, 1>::v;
        return Filt<0, 2>::v;
    } else if (s == 1) {
        if (d == 0) return Filt<1, 0>::v;
        if (d == 1) return Filt<1, 1>::v;
        if (d == 2) return Filt<1, 2>::v;
        if (d == 3) return Filt<1, 3>::v;
        return Filt<1, 4>::v;
    } else {
        if (d == 0) return Filt<2, 0>::v;
        if (d == 1) return Filt<2, 1>::v;
        if (d == 2) return Filt<2, 2>::v;
        if (d == 3) return Filt<2, 3>::v;
        if (d == 4) return Filt<2, 4>::v;
        if (d == 5) return Filt<2, 5>::v;
        if (d == 6) return Filt<2, 6>::v;
        if (d == 7) return Filt<2, 7>::v;
        return Filt<2, 8>::v;
    }
}

// Packed mirror-pair tables (algebra verified rounds 3-9):
// point-antisymmetry G(-u,-v) = -G(u,v); x-mirror G_{nd-d}(u,v) = G_d(u,-v).
// out_d = P + Q, out_{nd-d} = P - Q;
//   A(j,k) = (G_dP(u,v)+G_dP(u,-v))/2, dP = (k==0 ? NH : k)
//   B(j,k) = (G_dQ(u,v)-G_dQ(u,-v))/2, dQ = (k==0 ? 0  : k)
// positions j: 0..6 (0,v) [A==0], 7..13 (u,0) [B==0], 14..62 (u,v) u,v>=1.
template <int NH> struct PTab { float a[63 * NH]; float b[63 * NH]; };

template <int NH>
constexpr PTab<NH> make_ptab(int s) {
    PTab<NH> t{};
    for (int j = 0; j < 63; ++j) {
        int u, v;
        if (j < 7)       { u = 0;     v = j + 1; }
        else if (j < 14) { u = j - 6; v = 0;     }
        else { int p = j - 14; u = p / 7 + 1; v = p % 7 + 1; }
        for (int k = 0; k < NH; ++k) {
            int dP = (k == 0) ? NH : k;
            int dQ = (k == 0) ? 0 : k;
            const F225& FP = getF(s, dP);
            const F225& FQ = getF(s, dQ);
            double A = 0.5 * (FP.v[(7 + u) * 15 + (7 + v)] + FP.v[(7 + u) * 15 + (7 - v)]);
            double B = 0.5 * (FQ.v[(7 + u) * 15 + (7 + v)] - FQ.v[(7 + u) * 15 + (7 - v)]);
            t.a[j * NH + k] = (float)A;
            t.b[j * NH + k] = (float)B;
        }
    }
    return t;
}
template <int S, int NH>
struct PTbl { static constexpr PTab<NH> t = make_ptab<NH>(S); };

// ===================== scalar-fmac building blocks ==========================
// VOP2 v_fmac_f32 with the coefficient as a 32-bit literal in src0: exactly
// ONE issue per FMA, zero operand setup. (Round-9 lesson: v_pk_fma_f32 needs
// SGPR-pair constants -> 2 s_mov in the same wave's serial issue stream ->
// no net win + dependency stalls. VOP3P literals are illegal on gfx950.)
constexpr unsigned fb(float f) { return __builtin_bit_cast(unsigned, f); }

template <unsigned B>
__device__ __forceinline__ void fmac(float& a, float s) {
    asm("v_fmac_f32 %0, %2, %1" : "+v"(a) : "v"(s), "n"(B));
}

// Single stream at position J over all PX pixels (USEA -> A table else B).
template <int SIDX, int NH, int J, int PX, bool USEA, int K = 0>
struct AccOne {
    static __device__ __forceinline__ void run(float (&T)[PX][NH], const float (&val)[PX]) {
        constexpr unsigned b = USEA ? fb(PTbl<SIDX, NH>::t.a[J * NH + K])
                                    : fb(PTbl<SIDX, NH>::t.b[J * NH + K]);
#pragma unroll
        for (int j = 0; j < PX; ++j) fmac<b>(T[j][K], val[j]);
        if constexpr (K + 1 < NH) AccOne<SIDX, NH, J, PX, USEA, K + 1>::run(T, val);
    }
};
// Both streams at position J: S -> P (A coefs), D -> Q (B coefs).
template <int SIDX, int NH, int J, int PX, int K = 0>
struct AccSD {
    static __device__ __forceinline__ void run(float (&P)[PX][NH], float (&Q)[PX][NH],
                                               const float (&S)[PX], const float (&D)[PX]) {
        constexpr unsigned bA = fb(PTbl<SIDX, NH>::t.a[J * NH + K]);
        constexpr unsigned bB = fb(PTbl<SIDX, NH>::t.b[J * NH + K]);
#pragma unroll
        for (int j = 0; j < PX; ++j) fmac<bA>(P[j][K], S[j]);
#pragma unroll
        for (int j = 0; j < PX; ++j) fmac<bB>(Q[j][K], D[j]);
        if constexpr (K + 1 < NH) AccSD<SIDX, NH, J, PX, K + 1>::run(P, Q, S, D);
    }
};

// H0: u=0, v=1..7 (j=v-1): A==0, Q only.
template <int SIDX, int NH, int PX, int W, int V = 1>
struct H0Step {
    static __device__ __forceinline__ void run(const float (&w0)[W], float (&Q)[PX][NH]) {
        float dv[PX];
#pragma unroll
        for (int j = 0; j < PX; ++j) dv[j] = w0[7 + V + j] - w0[7 - V + j];
        AccOne<SIDX, NH, V - 1, PX, false>::run(Q, dv);
        if constexpr (V < 7) H0Step<SIDX, NH, PX, W, V + 1>::run(w0, Q);
    }
};

// Hp: v=1..7 for one u: S->P, D->Q.
template <int SIDX, int NH, int PX, int W, int U, int V = 1>
struct VStep {
    static __device__ __forceinline__ void run(const float (&wp)[W], const float (&wm)[W],
                                               float (&P)[PX][NH], float (&Q)[PX][NH]) {
        float S[PX], D[PX];
#pragma unroll
        for (int j = 0; j < PX; ++j) {
            float t1 = wp[7 + V + j] - wm[7 - V + j];
            float t2 = wp[7 - V + j] - wm[7 + V + j];
            S[j] = t1 + t2;
            D[j] = t1 - t2;
        }
        AccSD<SIDX, NH, 14 + (U - 1) * 7 + (V - 1), PX>::run(P, Q, S, D);
        if constexpr (V < 7) VStep<SIDX, NH, PX, W, U, V + 1>::run(wp, wm, P, Q);
    }
};

// u = 1..7. Per u-step: load the two row windows ONCE into registers
// (compiler merges consecutive scalar LDS reads into ds_read2_b32 — ~2x
// fewer DS issues than per-position loads). Memory-clobber fence per u-step
// bounds the scheduling window (round-5 lesson: unfenced body spills).
template <int SIDX, int NH, int PX, int W, int U = 1>
struct UStep {
    static __device__ __forceinline__ void run(const float* sm, int yb, int xg,
                                               float (&P)[PX][NH], float (&Q)[PX][NH]) {
        float wp[W], wm[W];
#pragma unroll
        for (int i = 0; i < W; ++i) wp[i] = sm[(yb + U) * 49 + xg + i];
#pragma unroll
        for (int i = 0; i < W; ++i) wm[i] = sm[(yb - U) * 49 + xg + i];
        {   // Hc: v=0 (j=6+U): B==0, P only
            float dvc[PX];
#pragma unroll
            for (int j = 0; j < PX; ++j) dvc[j] = wp[7 + j] - wm[7 + j];
            AccOne<SIDX, NH, 6 + U, PX, true>::run(P, dvc);
        }
        VStep<SIDX, NH, PX, W, U>::run(wp, wm, P, Q);
        asm volatile("" ::: "memory");
        if constexpr (U < 7) UStep<SIDX, NH, PX, W, U + 1>::run(sm, yb, xg, P, Q);
    }
};

// vectorized store of PX adjacent floats (16B/8B aligned by construction)
template <int PX>
__device__ __forceinline__ void stpx(float* p, const float (&vals)[PX]) {
    if constexpr (PX == 4) {
        v4f t; t.x = vals[0]; t.y = vals[1]; t.z = vals[2]; t.w = vals[3];
        *reinterpret_cast<v4f*>(p) = t;
    } else {
        v2f t; t.x = vals[0]; t.y = vals[1];
        *reinterpret_cast<v2f*>(p) = t;
    }
}

// One band over a 32x32 tile. PX adjacent x-pixels per thread; 4/PX row-iters.
// PX=4 for NH=2,4 (windows amortized over 4 px, single pass); PX=2 for NH=8
// (VGPR control). sm: flat LDS band tile, stride 49, halo 7.
template <int SIDX, int NH, int PX>
__device__ __forceinline__ void dir_band(
    const float* sm, float* __restrict__ out, long nbase,
    int by, int bx, int lane, int c0) {
    constexpr int W = 14 + PX;
    constexpr int LPR = 32 / PX;   // threads per tile row
    int xg = (lane % LPR) * PX;
    int yr = lane / LPR;
#pragma unroll 1
    for (int rr = 0; rr < 4 / PX; ++rr) {
        int y = yr + 8 * PX * rr;
        int yb = y + 7;
        float P[PX][NH], Q[PX][NH];
#pragma unroll
        for (int j = 0; j < PX; ++j)
#pragma unroll
            for (int k = 0; k < NH; ++k) { P[j][k] = 0.f; Q[j][k] = 0.f; }
        {
            float w0[W];
#pragma unroll
            for (int i = 0; i < W; ++i) w0[i] = sm[yb * 49 + xg + i];
            H0Step<SIDX, NH, PX, W>::run(w0, Q);
        }
        asm volatile("" ::: "memory");
        UStep<SIDX, NH, PX, W>::run(sm, yb, xg, P, Q);

        // d=0 -> Q[0]; d=NH -> P[0]; pair k: d=k -> P+Q, d=2NH-k -> P-Q
        long idx0 = nbase + (long)c0 * HWSZ + (long)(by + y) * WW + bx + xg;
        {
            float o[PX];
#pragma unroll
            for (int j = 0; j < PX; ++j) o[j] = Q[j][0];
            stpx<PX>(out + idx0, o);
#pragma unroll
            for (int j = 0; j < PX; ++j) o[j] = P[j][0];
            stpx<PX>(out + idx0 + (long)NH * HWSZ, o);
        }
#pragma unroll
        for (int k = 1; k < NH; ++k) {
            float op[PX], om[PX];
#pragma unroll
            for (int j = 0; j < PX; ++j) {
                op[j] = P[j][k] + Q[j][k];
                om[j] = P[j][k] - Q[j][k];
            }
            stpx<PX>(out + idx0 + (long)k * HWSZ, op);
            stpx<PX>(out + idx0 + (long)(2 * NH - k) * HWSZ, om);
        }
    }
}

// ===================== fully-fused NSST kernel ==============================
// Per 32x32 tile: stage x with halo 13 (reflect) -> lp chain in LDS ->
// band0/1/2 materialized in LDS (stride 49) -> three dir banks. Zero
// intermediate HBM traffic. Buffer recycling:
//   Xb: x[58][60]            -> lp1[50][52]
//   Tb: h0[58][56] -> band0[46][49] -> h1[54][52] -> band1 -> h2[50][48] -> band2
//   Pb: lp0[54][56]          -> lp2[46][48]
__global__ __launch_bounds__(256, 4) void nsst_fused(
    const float* __restrict__ x, float* __restrict__ out) {
    __shared__ float Xb[58 * 60];
    __shared__ float Tb[58 * 56];
    __shared__ float Pb[54 * 56];

    int n = blockIdx.z;
    int bx = blockIdx.x * 32, by = blockIdx.y * 32;
    int tx = threadIdx.x, ty = threadIdx.y;
    int lane = ty * 32 + tx;
    const float* ip = x + (long)n * HWSZ;
    long nbase = (long)n * 29 * HWSZ;

    // stage x[-13..44]^2 (58x58), reflect at input indexing (2D strides: no div)
    for (int r = ty; r < 58; r += 8) {
        int gy = refl(by + r - 13, HH);
        for (int c = tx; c < 58; c += 32)
            Xb[r * 60 + c] = ip[(long)gy * WW + refl(bx + c - 13, WW)];
    }
    __syncthreads();
    // h0 = H(x): 58 rows x 54 cols, Tb stride 56
    for (int r = ty; r < 58; r += 8)
        for (int c = tx; c < 54; c += 32) {
            float s = 0.f;
#pragma unroll
            for (int i = 0; i < 5; ++i) s = fmaf(LPW[i], Xb[r * 60 + c + i], s);
            Tb[r * 56 + c] = s;
        }
    __syncthreads();
    // lp0 = V(h0): 54x54, Pb stride 56
    for (int r = ty; r < 54; r += 8)
        for (int c = tx; c < 54; c += 32) {
            float s = 0.f;
#pragma unroll
            for (int i = 0; i < 5; ++i) s = fmaf(LPW[i], Tb[(r + i) * 56 + c], s);
            Pb[r * 56 + c] = s;
        }
    __syncthreads();
    // band0 = x - lp0 on 46x46, Tb stride 49
    for (int r = ty; r < 46; r += 8)
        for (int c = tx; c < 46; c += 32)
            Tb[r * 49 + c] = Xb[(r + 6) * 60 + c + 6] - Pb[(r + 4) * 56 + c + 4];
    __syncthreads();
    dir_band<0, 2, 4>(Tb, out, nbase, by, bx, lane, 0);   // channels 0..3
    __syncthreads();
    // h1 = H(lp0): 54 rows x 50 cols, Tb stride 52
    for (int r = ty; r < 54; r += 8)
        for (int c = tx; c < 50; c += 32) {
            float s = 0.f;
#pragma unroll
            for (int i = 0; i < 5; ++i) s = fmaf(LPW[i], Pb[r * 56 + c + i], s);
            Tb[r * 52 + c] = s;
        }
    __syncthreads();
    // lp1 = V(h1): 50x50, Xb stride 52 (x is dead)
    for (int r = ty; r < 50; r += 8)
        for (int c = tx; c < 50; c += 32) {
            float s = 0.f;
#pragma unroll
            for (int i = 0; i < 5; ++i) s = fmaf(LPW[i], Tb[(r + i) * 52 + c], s);
            Xb[r * 52 + c] = s;
        }
    __syncthreads();
    // band1 = lp0 - lp1 on 46x46, Tb stride 49
    for (int r = ty; r < 46; r += 8)
        for (int c = tx; c < 46; c += 32)
            Tb[r * 49 + c] = Pb[(r + 4) * 56 + c + 4] - Xb[(r + 2) * 52 + c + 2];
    __syncthreads();
    dir_band<1, 4, 4>(Tb, out, nbase, by, bx, lane, 4);   // channels 4..11
    __syncthreads();
    // h2 = H(lp1): 50 rows x 46 cols, Tb stride 48
    for (int r = ty; r < 50; r += 8)
        for (int c = tx; c < 46; c += 32) {
            float s = 0.f;
#pragma unroll
            for (int i = 0; i < 5; ++i) s = fmaf(LPW[i], Xb[r * 52 + c + i], s);
            Tb[r * 48 + c] = s;
        }
    __syncthreads();
    // lp2 = V(h2): 46x46, Pb stride 48 (lp0 dead)
    for (int r = ty; r < 46; r += 8)
        for (int c = tx; c < 46; c += 32) {
            float s = 0.f;
#pragma unroll
            for (int i = 0; i < 5; ++i) s = fmaf(LPW[i], Tb[(r + i) * 48 + c], s);
            Pb[r * 48 + c] = s;
        }
    __syncthreads();
    // channel 28 = lp2 center
#pragma unroll
    for (int rr = 0; rr < 4; ++rr)
        out[nbase + 28l * HWSZ + (long)(by + ty + 8 * rr) * WW + bx + tx] =
            Pb[(ty + 8 * rr + 7) * 48 + tx + 7];
    // band2 = lp1 - lp2 on 46x46, Tb stride 49 (h2 dead)
    for (int r = ty; r < 46; r += 8)
        for (int c = tx; c < 46; c += 32)
            Tb[r * 49 + c] = Xb[(r + 2) * 52 + c + 2] - Pb[r * 48 + c];
    __syncthreads();
    dir_band<2, 8, 2>(Tb, out, nbase, by, bx, lane, 12);  // channels 12..27
}

extern "C" void kernel_launch(void* const* d_in, const int* in_sizes, int n_in,
                              void* d_out, int out_size, void* d_ws, size_t ws_size,
                              hipStream_t stream) {
    const float* x = (const float*)d_in[0];
    float* out = (float*)d_out;
    (void)d_ws; (void)ws_size;

    nsst_fused<<<dim3(12, 12, NIMG), dim3(32, 8), 0, stream>>>(x, out);
}